// Round 3
// baseline (237.362 us; speedup 1.0000x reference)
//
#include <hip/hip_runtime.h>

typedef unsigned short ushort_t;
typedef __bf16 bf16x8 __attribute__((ext_vector_type(8)));
typedef float f32x4 __attribute__((ext_vector_type(4)));
typedef unsigned int uint4v __attribute__((ext_vector_type(4)));
typedef unsigned int uint2v __attribute__((ext_vector_type(2)));

#define NTOK 4096
#define DMODEL 256
#define DK 64
#define BS 8

__device__ __forceinline__ ushort_t f2bf(float f) {
  unsigned u = __builtin_bit_cast(unsigned, f);
  u += 0x7fffu + ((u >> 16) & 1u);
  return (ushort_t)(u >> 16);
}
__device__ __forceinline__ bf16x8 lds_frag(const ushort_t* p) {
  return __builtin_bit_cast(bf16x8, *(const uint4v*)p);
}

// ---------------- k_convert: Wqkv, Wout fp32 -> bf16 in ws ----------------
__global__ __launch_bounds__(256) void k_convert(const float* __restrict__ Wqkv,
                                                 const float* __restrict__ Wout,
                                                 ushort_t* __restrict__ Wb,
                                                 ushort_t* __restrict__ Woutb) {
  int i = blockIdx.x * 256 + threadIdx.x;  // 256 blocks: 65536 total
  if (i < 3 * DK * DMODEL) {
    Wb[i] = f2bf(Wqkv[i]);
  } else {
    int j = i - 3 * DK * DMODEL;
    Woutb[j] = f2bf(Wout[j]);
  }
}

// -------- k0: transpose x[b][c][n] (fp32) -> xT[b][n][c] (bf16) -----------
__global__ __launch_bounds__(256) void k_transpose(const float* __restrict__ x,
                                                   ushort_t* __restrict__ xT) {
  const int b = blockIdx.z;
  const int c0 = blockIdx.y * 64;
  const int n0 = blockIdx.x * 64;
  const int tid = threadIdx.x;
  __shared__ __align__(16) ushort_t t[64 * 72];
  const float* xb = x + (size_t)b * DMODEL * NTOK;
  ushort_t* xTb = xT + (size_t)b * NTOK * DMODEL;
#pragma unroll
  for (int kr = 0; kr < 2; kr++) {
    int s = tid + 256 * kr;
    int c = s >> 3, ns = (s & 7) * 8;
    const float* src = xb + (size_t)(c0 + c) * NTOK + n0 + ns;
    f32x4 a = *(const f32x4*)src;
    f32x4 bq = *(const f32x4*)(src + 4);
    uint4v o;
    o.x = (unsigned)f2bf(a[0]) | ((unsigned)f2bf(a[1]) << 16);
    o.y = (unsigned)f2bf(a[2]) | ((unsigned)f2bf(a[3]) << 16);
    o.z = (unsigned)f2bf(bq[0]) | ((unsigned)f2bf(bq[1]) << 16);
    o.w = (unsigned)f2bf(bq[2]) | ((unsigned)f2bf(bq[3]) << 16);
    *(uint4v*)(t + c * 72 + ns) = o;
  }
  __syncthreads();
#pragma unroll
  for (int kr = 0; kr < 2; kr++) {
    int s = tid + 256 * kr;
    int n = s >> 3, cs = (s & 7) * 8;
    unsigned e0 = t[(cs + 0) * 72 + n], e1 = t[(cs + 1) * 72 + n];
    unsigned e2 = t[(cs + 2) * 72 + n], e3 = t[(cs + 3) * 72 + n];
    unsigned e4 = t[(cs + 4) * 72 + n], e5 = t[(cs + 5) * 72 + n];
    unsigned e6 = t[(cs + 6) * 72 + n], e7 = t[(cs + 7) * 72 + n];
    uint4v o;
    o.x = e0 | (e1 << 16); o.y = e2 | (e3 << 16);
    o.z = e4 | (e5 << 16); o.w = e6 | (e7 << 16);
    *(uint4v*)(xTb + (size_t)(n0 + n) * DMODEL + c0 + cs) = o;
  }
}

// ---------------- k1: qkv = Wqkv @ x ; store QT,KT (transposed) and V -----
__global__ __launch_bounds__(256) void k_qkv(const ushort_t* __restrict__ xT,
                                             const ushort_t* __restrict__ W,
                                             ushort_t* __restrict__ QT,
                                             ushort_t* __restrict__ KT,
                                             ushort_t* __restrict__ Vv) {
  const int b = blockIdx.y;
  const int n0 = blockIdx.x * 64;
  const int tid = threadIdx.x;
  const int lane = tid & 63, wv = tid >> 6;
  const int quad = lane >> 4, l15 = lane & 15;
  __shared__ __align__(16) ushort_t lw[192 * 40];  // W chunk [192 o][32 c] pad->40
  __shared__ __align__(16) ushort_t lx[64 * 40];   // xT chunk [64 n][32 c] pad->40
  f32x4 acc[3][4];
  const f32x4 zero4 = {0.f, 0.f, 0.f, 0.f};
#pragma unroll
  for (int i = 0; i < 3; i++)
#pragma unroll
    for (int j = 0; j < 4; j++) acc[i][j] = zero4;

  const ushort_t* xTb = xT + ((size_t)b * NTOK + n0) * DMODEL;

  for (int c0 = 0; c0 < DMODEL; c0 += 32) {
    __syncthreads();
#pragma unroll
    for (int kr = 0; kr < 3; kr++) {
      int s = tid + 256 * kr;
      int o = s >> 2, cs = (s & 3) * 8;
      *(uint4v*)(lw + o * 40 + cs) = *(const uint4v*)(W + o * DMODEL + c0 + cs);
    }
    {
      int n = tid >> 2, cs = (tid & 3) * 8;
      *(uint4v*)(lx + n * 40 + cs) = *(const uint4v*)(xTb + (size_t)n * DMODEL + c0 + cs);
    }
    __syncthreads();
    bf16x8 bb[4];
#pragma unroll
    for (int nt = 0; nt < 4; nt++) bb[nt] = lds_frag(lx + (nt * 16 + l15) * 40 + quad * 8);
#pragma unroll
    for (int mt = 0; mt < 3; mt++) {
      bf16x8 a = lds_frag(lw + (wv * 48 + mt * 16 + l15) * 40 + quad * 8);
#pragma unroll
      for (int nt = 0; nt < 4; nt++)
        acc[mt][nt] = __builtin_amdgcn_mfma_f32_16x16x32_bf16(a, bb[nt], acc[mt][nt], 0, 0, 0);
    }
  }
#pragma unroll
  for (int mt = 0; mt < 3; mt++) {
    int o = wv * 48 + mt * 16 + quad * 4;
#pragma unroll
    for (int nt = 0; nt < 4; nt++) {
      int n = n0 + nt * 16 + l15;
      f32x4 v4 = acc[mt][nt];
      if (o < 128) {
        ushort_t* dst = (o < 64) ? (QT + ((size_t)b * NTOK + n) * DK + o)
                                 : (KT + ((size_t)b * NTOK + n) * DK + (o - 64));
        uint2v ww;
        ww.x = (unsigned)f2bf(v4[0]) | ((unsigned)f2bf(v4[1]) << 16);
        ww.y = (unsigned)f2bf(v4[2]) | ((unsigned)f2bf(v4[3]) << 16);
        *(uint2v*)dst = ww;
      } else {
        int d = o - 128;
#pragma unroll
        for (int r = 0; r < 4; r++)
          Vv[((size_t)b * DK + d + r) * NTOK + n] = f2bf(v4[r]);
      }
    }
  }
}

// ---------------- k2: r_i = 1 / sum_j exp(q_i . k_j) ----------------------
__global__ __launch_bounds__(256) void k_stats(const ushort_t* __restrict__ QT,
                                               const ushort_t* __restrict__ KT,
                                               float* __restrict__ R) {
  const int b = blockIdx.y;
  const int i0 = blockIdx.x * 64;
  const int tid = threadIdx.x;
  const int lane = tid & 63, wv = tid >> 6;
  const int quad = lane >> 4, l15 = lane & 15;
  __shared__ __align__(16) ushort_t lq[64 * 72];
  __shared__ __align__(16) ushort_t lk[2][64 * 72];
  const ushort_t* QTb = QT + ((size_t)b * NTOK + i0) * DK;
  const ushort_t* KTb = KT + (size_t)b * NTOK * DK;
#pragma unroll
  for (int kr = 0; kr < 2; kr++) {
    int s = tid + 256 * kr;
    int row = s >> 3, ds = (s & 7) * 8;
    *(uint4v*)(lq + row * 72 + ds) = *(const uint4v*)(QTb + (size_t)row * DK + ds);
    *(uint4v*)(lk[0] + row * 72 + ds) = *(const uint4v*)(KTb + (size_t)row * DK + ds);
  }
  __syncthreads();
  bf16x8 a0 = lds_frag(lq + (wv * 16 + l15) * 72 + quad * 8);
  bf16x8 a1 = lds_frag(lq + (wv * 16 + l15) * 72 + 32 + quad * 8);
  float lsum0 = 0.f, lsum1 = 0.f, lsum2 = 0.f, lsum3 = 0.f;
  const f32x4 zero4 = {0.f, 0.f, 0.f, 0.f};
  for (int it = 0; it < 64; it++) {
    if (it + 1 < 64) {
      const ushort_t* src = KTb + (size_t)(it + 1) * 64 * DK;
      ushort_t* dstb = lk[(it + 1) & 1];
#pragma unroll
      for (int kr = 0; kr < 2; kr++) {
        int s = tid + 256 * kr;
        int row = s >> 3, ds = (s & 7) * 8;
        *(uint4v*)(dstb + row * 72 + ds) = *(const uint4v*)(src + (size_t)row * DK + ds);
      }
    }
    const ushort_t* kb = lk[it & 1];
#pragma unroll
    for (int nt = 0; nt < 4; nt++) {
      bf16x8 b0 = lds_frag(kb + (nt * 16 + l15) * 72 + quad * 8);
      bf16x8 b1 = lds_frag(kb + (nt * 16 + l15) * 72 + 32 + quad * 8);
      f32x4 s4 = __builtin_amdgcn_mfma_f32_16x16x32_bf16(a0, b0, zero4, 0, 0, 0);
      s4 = __builtin_amdgcn_mfma_f32_16x16x32_bf16(a1, b1, s4, 0, 0, 0);
      lsum0 += __expf(s4[0]);
      lsum1 += __expf(s4[1]);
      lsum2 += __expf(s4[2]);
      lsum3 += __expf(s4[3]);
    }
    __syncthreads();
  }
#pragma unroll
  for (int off = 1; off < 16; off <<= 1) {
    lsum0 += __shfl_xor(lsum0, off);
    lsum1 += __shfl_xor(lsum1, off);
    lsum2 += __shfl_xor(lsum2, off);
    lsum3 += __shfl_xor(lsum3, off);
  }
  if (l15 < 4) {
    float v = (l15 == 0) ? lsum0 : (l15 == 1) ? lsum1 : (l15 == 2) ? lsum2 : lsum3;
    R[(size_t)b * NTOK + i0 + wv * 16 + quad * 4 + l15] = 1.0f / v;
  }
}

// ---------------- k3: y = V @ (exp(S)*r), o = Wout@y*gamma + x ------------
__global__ __launch_bounds__(256) void k_attn(const ushort_t* __restrict__ QT,
                                              const ushort_t* __restrict__ KT,
                                              const ushort_t* __restrict__ Vv,
                                              const float* __restrict__ R,
                                              const ushort_t* __restrict__ Wout,
                                              const float* __restrict__ gammap,
                                              const float* __restrict__ x,
                                              float* __restrict__ outp) {
  const int b = blockIdx.y;
  const int j0 = blockIdx.x * 64;
  const int tid = threadIdx.x;
  const int lane = tid & 63, wv = tid >> 6;
  const int quad = lane >> 4, l15 = lane & 15;
  __shared__ __align__(16) ushort_t lkt[64 * 72];
  __shared__ __align__(16) ushort_t lq[2][64 * 72];
  __shared__ __align__(16) ushort_t lv[2][64 * 72];
  __shared__ __align__(16) ushort_t lp[64 * 72];
  __shared__ float lr[2][64];

  const ushort_t* KTb = KT + ((size_t)b * NTOK + j0) * DK;
  const ushort_t* QTb = QT + (size_t)b * NTOK * DK;
  const ushort_t* Vb = Vv + (size_t)b * DK * NTOK;
  const float* Rb = R + (size_t)b * NTOK;

#pragma unroll
  for (int kr = 0; kr < 2; kr++) {
    int s = tid + 256 * kr;
    int row = s >> 3, ds = (s & 7) * 8;
    *(uint4v*)(lkt + row * 72 + ds) = *(const uint4v*)(KTb + (size_t)row * DK + ds);
    *(uint4v*)(lq[0] + row * 72 + ds) = *(const uint4v*)(QTb + (size_t)row * DK + ds);
    *(uint4v*)(lv[0] + row * 72 + ds) = *(const uint4v*)(Vb + (size_t)row * NTOK + ds);
  }
  if (tid < 64) lr[0][tid] = Rb[tid];
  __syncthreads();

  bf16x8 kb0[4], kb1[4];
#pragma unroll
  for (int nt = 0; nt < 4; nt++) {
    kb0[nt] = lds_frag(lkt + (nt * 16 + l15) * 72 + quad * 8);
    kb1[nt] = lds_frag(lkt + (nt * 16 + l15) * 72 + 32 + quad * 8);
  }
  const f32x4 zero4 = {0.f, 0.f, 0.f, 0.f};
  f32x4 yacc[4];
#pragma unroll
  for (int nt = 0; nt < 4; nt++) yacc[nt] = zero4;

  for (int it = 0; it < 64; it++) {
    const int cb = it & 1, nb = cb ^ 1;
    if (it + 1 < 64) {
      const ushort_t* qsrc = QTb + (size_t)(it + 1) * 64 * DK;
      const ushort_t* vsrc = Vb + (it + 1) * 64;
#pragma unroll
      for (int kr = 0; kr < 2; kr++) {
        int s = tid + 256 * kr;
        int row = s >> 3, ds = (s & 7) * 8;
        *(uint4v*)(lq[nb] + row * 72 + ds) = *(const uint4v*)(qsrc + (size_t)row * DK + ds);
        *(uint4v*)(lv[nb] + row * 72 + ds) = *(const uint4v*)(vsrc + (size_t)row * NTOK + ds);
      }
      if (tid < 64) lr[nb][tid] = Rb[(it + 1) * 64 + tid];
    }
    // S tile: rows i (this wave: 16*wv..+15), cols j (64)
    bf16x8 a0 = lds_frag(lq[cb] + (wv * 16 + l15) * 72 + quad * 8);
    bf16x8 a1 = lds_frag(lq[cb] + (wv * 16 + l15) * 72 + 32 + quad * 8);
    float rv0 = lr[cb][wv * 16 + quad * 4 + 0];
    float rv1 = lr[cb][wv * 16 + quad * 4 + 1];
    float rv2 = lr[cb][wv * 16 + quad * 4 + 2];
    float rv3 = lr[cb][wv * 16 + quad * 4 + 3];
#pragma unroll
    for (int nt = 0; nt < 4; nt++) {
      f32x4 s4 = __builtin_amdgcn_mfma_f32_16x16x32_bf16(a0, kb0[nt], zero4, 0, 0, 0);
      s4 = __builtin_amdgcn_mfma_f32_16x16x32_bf16(a1, kb1[nt], s4, 0, 0, 0);
      uint2v ww;
      ww.x = (unsigned)f2bf(__expf(s4[0]) * rv0) | ((unsigned)f2bf(__expf(s4[1]) * rv1) << 16);
      ww.y = (unsigned)f2bf(__expf(s4[2]) * rv2) | ((unsigned)f2bf(__expf(s4[3]) * rv3) << 16);
      *(uint2v*)(lp + (nt * 16 + l15) * 72 + wv * 16 + quad * 4) = ww;
    }
    __syncthreads();  // lp ready
    // PV: y[d][j] += V[d][i] * w[i][j]; this wave: d rows 16*wv..+15
    bf16x8 av0 = lds_frag(lv[cb] + (wv * 16 + l15) * 72 + quad * 8);
    bf16x8 av1 = lds_frag(lv[cb] + (wv * 16 + l15) * 72 + 32 + quad * 8);
#pragma unroll
    for (int nt = 0; nt < 4; nt++) {
      bf16x8 p0 = lds_frag(lp + (nt * 16 + l15) * 72 + quad * 8);
      bf16x8 p1 = lds_frag(lp + (nt * 16 + l15) * 72 + 32 + quad * 8);
      yacc[nt] = __builtin_amdgcn_mfma_f32_16x16x32_bf16(av0, p0, yacc[nt], 0, 0, 0);
      yacc[nt] = __builtin_amdgcn_mfma_f32_16x16x32_bf16(av1, p1, yacc[nt], 0, 0, 0);
    }
    __syncthreads();  // lp reads done; staged buffers safe to rotate
  }

  // epilogue: yT into lp (reuse), then o = Wout @ y * gamma + x
#pragma unroll
  for (int nt = 0; nt < 4; nt++) {
    f32x4 v4 = yacc[nt];
    uint2v ww;
    ww.x = (unsigned)f2bf(v4[0]) | ((unsigned)f2bf(v4[1]) << 16);
    ww.y = (unsigned)f2bf(v4[2]) | ((unsigned)f2bf(v4[3]) << 16);
    *(uint2v*)(lp + (nt * 16 + l15) * 72 + wv * 16 + quad * 4) = ww;
  }
  __syncthreads();
  bf16x8 yb0[4], yb1[4];
#pragma unroll
  for (int nt = 0; nt < 4; nt++) {
    yb0[nt] = lds_frag(lp + (nt * 16 + l15) * 72 + quad * 8);
    yb1[nt] = lds_frag(lp + (nt * 16 + l15) * 72 + 32 + quad * 8);
  }
  f32x4 oacc[4][4];
#pragma unroll
  for (int m = 0; m < 4; m++)
#pragma unroll
    for (int nt = 0; nt < 4; nt++) oacc[m][nt] = zero4;
#pragma unroll
  for (int m = 0; m < 4; m++) {
    int c = (wv * 4 + m) * 16 + l15;
    bf16x8 aw0 = __builtin_bit_cast(bf16x8, *(const uint4v*)(Wout + c * DK + quad * 8));
    bf16x8 aw1 = __builtin_bit_cast(bf16x8, *(const uint4v*)(Wout + c * DK + 32 + quad * 8));
#pragma unroll
    for (int nt = 0; nt < 4; nt++) {
      oacc[m][nt] = __builtin_amdgcn_mfma_f32_16x16x32_bf16(aw0, yb0[nt], oacc[m][nt], 0, 0, 0);
      oacc[m][nt] = __builtin_amdgcn_mfma_f32_16x16x32_bf16(aw1, yb1[nt], oacc[m][nt], 0, 0, 0);
    }
  }
  float g = gammap[0];
  const float* xb = x + (size_t)b * DMODEL * NTOK;
  float* ob = outp + (size_t)b * DMODEL * NTOK;
#pragma unroll
  for (int m = 0; m < 4; m++) {
    int cbase = (wv * 4 + m) * 16 + quad * 4;
#pragma unroll
    for (int nt = 0; nt < 4; nt++) {
      int n = j0 + nt * 16 + l15;
#pragma unroll
      for (int r = 0; r < 4; r++) {
        size_t idx = (size_t)(cbase + r) * NTOK + n;
        ob[idx] = oacc[m][nt][r] * g + xb[idx];
      }
    }
  }
}

extern "C" void kernel_launch(void* const* d_in, const int* in_sizes, int n_in,
                              void* d_out, int out_size, void* d_ws, size_t ws_size,
                              hipStream_t stream) {
  const float* v = (const float*)d_in[0];
  const float* Wqkv = (const float*)d_in[1];
  const float* Wout = (const float*)d_in[2];
  const float* gamma = (const float*)d_in[3];
  float* outp = (float*)d_out;

  ushort_t* xT = (ushort_t*)d_ws;                      // 8*4096*256 bf16
  ushort_t* QT = xT + (size_t)BS * NTOK * DMODEL;      // 8*4096*64
  ushort_t* KT = QT + (size_t)BS * NTOK * DK;
  ushort_t* Vs = KT + (size_t)BS * NTOK * DK;
  float* R = (float*)(Vs + (size_t)BS * DK * NTOK);    // 8*4096 f32
  ushort_t* Wb = (ushort_t*)(R + (size_t)BS * NTOK);   // 192*256 bf16
  ushort_t* Woutb = Wb + 3 * DK * DMODEL;              // 256*64 bf16

  k_convert<<<dim3(256), 256, 0, stream>>>(Wqkv, Wout, Wb, Woutb);
  k_transpose<<<dim3(64, 4, BS), 256, 0, stream>>>(v, xT);
  k_qkv<<<dim3(64, BS), 256, 0, stream>>>(xT, Wb, QT, KT, Vs);
  k_stats<<<dim3(64, BS), 256, 0, stream>>>(QT, KT, R);
  k_attn<<<dim3(64, BS), 256, 0, stream>>>(QT, KT, Vs, R, Woutb, gamma, v, outp);
}

// Round 6
// 221.897 us; speedup vs baseline: 1.0697x; 1.0697x over previous
//
#include <hip/hip_runtime.h>

typedef unsigned short ushort_t;
typedef __bf16 bf16x8 __attribute__((ext_vector_type(8)));
typedef short short4v __attribute__((ext_vector_type(4)));
typedef float f32x4 __attribute__((ext_vector_type(4)));
typedef unsigned int uint4v __attribute__((ext_vector_type(4)));
typedef unsigned int uint2v __attribute__((ext_vector_type(2)));

#define NTOK 4096
#define DMODEL 256
#define DK 64
#define BS 8

__device__ __forceinline__ ushort_t f2bf(float f) {
  unsigned u = __builtin_bit_cast(unsigned, f);
  u += 0x7fffu + ((u >> 16) & 1u);
  return (ushort_t)(u >> 16);
}
__device__ __forceinline__ float bf2f(ushort_t s) {
  return __builtin_bit_cast(float, ((unsigned)s) << 16);
}
__device__ __forceinline__ bf16x8 lds_frag(const ushort_t* p) {
  return __builtin_bit_cast(bf16x8, *(const uint4v*)p);
}
// K=16 bf16 MFMA: A[m=lane&15][k=quad*4+j], B[k=quad*4+j][n=lane&15], C: n=lane&15, m=quad*4+reg
__device__ __forceinline__ f32x4 mfma16(short4v a, short4v b, f32x4 c) {
#if defined(__HIP_DEVICE_COMPILE__)
#if __has_builtin(__builtin_amdgcn_mfma_f32_16x16x16bf16_1k)
  return __builtin_amdgcn_mfma_f32_16x16x16bf16_1k(a, b, c, 0, 0, 0);
#else
  typedef __bf16 bf16x4 __attribute__((ext_vector_type(4)));
  return __builtin_amdgcn_mfma_f32_16x16x16_bf16(__builtin_bit_cast(bf16x4, a),
                                                 __builtin_bit_cast(bf16x4, b), c, 0, 0, 0);
#endif
#else
  (void)a; (void)b;
  return c;  // host pass: never executed
#endif
}

// ---------------- k_convert: Wqkv, Wout fp32 -> bf16 in ws ----------------
__global__ __launch_bounds__(256) void k_convert(const float* __restrict__ Wqkv,
                                                 const float* __restrict__ Wout,
                                                 ushort_t* __restrict__ Wb,
                                                 ushort_t* __restrict__ Woutb) {
  int i = blockIdx.x * 256 + threadIdx.x;  // 256 blocks: 65536 total
  if (i < 3 * DK * DMODEL) {
    Wb[i] = f2bf(Wqkv[i]);
  } else {
    int j = i - 3 * DK * DMODEL;
    Woutb[j] = f2bf(Wout[j]);
  }
}

// -------- k0: transpose x[b][c][n] (fp32) -> xT[b][n][c] (bf16) -----------
__global__ __launch_bounds__(256) void k_transpose(const float* __restrict__ x,
                                                   ushort_t* __restrict__ xT) {
  const int b = blockIdx.z;
  const int c0 = blockIdx.y * 64;
  const int n0 = blockIdx.x * 64;
  const int tid = threadIdx.x;
  __shared__ __align__(16) ushort_t t[64 * 72];
  const float* xb = x + (size_t)b * DMODEL * NTOK;
  ushort_t* xTb = xT + (size_t)b * NTOK * DMODEL;
#pragma unroll
  for (int kr = 0; kr < 2; kr++) {
    int s = tid + 256 * kr;
    int c = s >> 3, ns = (s & 7) * 8;
    const float* src = xb + (size_t)(c0 + c) * NTOK + n0 + ns;
    f32x4 a = *(const f32x4*)src;
    f32x4 bq = *(const f32x4*)(src + 4);
    uint4v o;
    o.x = (unsigned)f2bf(a[0]) | ((unsigned)f2bf(a[1]) << 16);
    o.y = (unsigned)f2bf(a[2]) | ((unsigned)f2bf(a[3]) << 16);
    o.z = (unsigned)f2bf(bq[0]) | ((unsigned)f2bf(bq[1]) << 16);
    o.w = (unsigned)f2bf(bq[2]) | ((unsigned)f2bf(bq[3]) << 16);
    *(uint4v*)(t + c * 72 + ns) = o;
  }
  __syncthreads();
#pragma unroll
  for (int kr = 0; kr < 2; kr++) {
    int s = tid + 256 * kr;
    int n = s >> 3, cs = (s & 7) * 8;
    unsigned e0 = t[(cs + 0) * 72 + n], e1 = t[(cs + 1) * 72 + n];
    unsigned e2 = t[(cs + 2) * 72 + n], e3 = t[(cs + 3) * 72 + n];
    unsigned e4 = t[(cs + 4) * 72 + n], e5 = t[(cs + 5) * 72 + n];
    unsigned e6 = t[(cs + 6) * 72 + n], e7 = t[(cs + 7) * 72 + n];
    uint4v o;
    o.x = e0 | (e1 << 16); o.y = e2 | (e3 << 16);
    o.z = e4 | (e5 << 16); o.w = e6 | (e7 << 16);
    *(uint4v*)(xTb + (size_t)(n0 + n) * DMODEL + c0 + cs) = o;
  }
}

// ---------------- k1: qkv = Wqkv @ x ; store QT,KT (transposed) and V -----
__global__ __launch_bounds__(256) void k_qkv(const ushort_t* __restrict__ xT,
                                             const ushort_t* __restrict__ W,
                                             ushort_t* __restrict__ QT,
                                             ushort_t* __restrict__ KT,
                                             ushort_t* __restrict__ Vv) {
  const int b = blockIdx.y;
  const int n0 = blockIdx.x * 64;
  const int tid = threadIdx.x;
  const int lane = tid & 63, wv = tid >> 6;
  const int quad = lane >> 4, l15 = lane & 15;
  __shared__ __align__(16) ushort_t lw[192 * 40];  // W chunk [192 o][32 c] pad->40
  __shared__ __align__(16) ushort_t lx[64 * 40];   // xT chunk [64 n][32 c] pad->40
  f32x4 acc[3][4];
  const f32x4 zero4 = {0.f, 0.f, 0.f, 0.f};
#pragma unroll
  for (int i = 0; i < 3; i++)
#pragma unroll
    for (int j = 0; j < 4; j++) acc[i][j] = zero4;

  const ushort_t* xTb = xT + ((size_t)b * NTOK + n0) * DMODEL;

  for (int c0 = 0; c0 < DMODEL; c0 += 32) {
    __syncthreads();
#pragma unroll
    for (int kr = 0; kr < 3; kr++) {
      int s = tid + 256 * kr;
      int o = s >> 2, cs = (s & 3) * 8;
      *(uint4v*)(lw + o * 40 + cs) = *(const uint4v*)(W + o * DMODEL + c0 + cs);
    }
    {
      int n = tid >> 2, cs = (tid & 3) * 8;
      *(uint4v*)(lx + n * 40 + cs) = *(const uint4v*)(xTb + (size_t)n * DMODEL + c0 + cs);
    }
    __syncthreads();
    bf16x8 bb[4];
#pragma unroll
    for (int nt = 0; nt < 4; nt++) bb[nt] = lds_frag(lx + (nt * 16 + l15) * 40 + quad * 8);
#pragma unroll
    for (int mt = 0; mt < 3; mt++) {
      bf16x8 a = lds_frag(lw + (wv * 48 + mt * 16 + l15) * 40 + quad * 8);
#pragma unroll
      for (int nt = 0; nt < 4; nt++)
        acc[mt][nt] = __builtin_amdgcn_mfma_f32_16x16x32_bf16(a, bb[nt], acc[mt][nt], 0, 0, 0);
    }
  }
#pragma unroll
  for (int mt = 0; mt < 3; mt++) {
    int o = wv * 48 + mt * 16 + quad * 4;
#pragma unroll
    for (int nt = 0; nt < 4; nt++) {
      int n = n0 + nt * 16 + l15;
      f32x4 v4 = acc[mt][nt];
      if (o < 128) {
        ushort_t* dst = (o < 64) ? (QT + ((size_t)b * NTOK + n) * DK + o)
                                 : (KT + ((size_t)b * NTOK + n) * DK + (o - 64));
        uint2v ww;
        ww.x = (unsigned)f2bf(v4[0]) | ((unsigned)f2bf(v4[1]) << 16);
        ww.y = (unsigned)f2bf(v4[2]) | ((unsigned)f2bf(v4[3]) << 16);
        *(uint2v*)dst = ww;
      } else {
        int d = o - 128;
#pragma unroll
        for (int r = 0; r < 4; r++)
          Vv[((size_t)b * DK + d + r) * NTOK + n] = f2bf(v4[r]);
      }
    }
  }
}

// ------- k2: r_i = 1/sum_j exp(q_i.k_j); V[:,i] *= r_i (in place) ---------
__global__ __launch_bounds__(256) void k_stats(const ushort_t* __restrict__ QT,
                                               const ushort_t* __restrict__ KT,
                                               ushort_t* __restrict__ Vv) {
  const int b = blockIdx.y;
  const int i0 = blockIdx.x * 64;
  const int tid = threadIdx.x;
  const int lane = tid & 63, wv = tid >> 6;
  const int quad = lane >> 4, l15 = lane & 15;
  __shared__ __align__(16) ushort_t lq[64 * 72];
  __shared__ __align__(16) ushort_t lk[2][64 * 72];
  __shared__ float lrr[64];
  const ushort_t* QTb = QT + ((size_t)b * NTOK + i0) * DK;
  const ushort_t* KTb = KT + (size_t)b * NTOK * DK;
#pragma unroll
  for (int kr = 0; kr < 2; kr++) {
    int s = tid + 256 * kr;
    int row = s >> 3, ds = (s & 7) * 8;
    *(uint4v*)(lq + row * 72 + ds) = *(const uint4v*)(QTb + (size_t)row * DK + ds);
    *(uint4v*)(lk[0] + row * 72 + ds) = *(const uint4v*)(KTb + (size_t)row * DK + ds);
  }
  __syncthreads();
  bf16x8 a0 = lds_frag(lq + (wv * 16 + l15) * 72 + quad * 8);
  bf16x8 a1 = lds_frag(lq + (wv * 16 + l15) * 72 + 32 + quad * 8);
  float lsum0 = 0.f, lsum1 = 0.f, lsum2 = 0.f, lsum3 = 0.f;
  const f32x4 zero4 = {0.f, 0.f, 0.f, 0.f};
  for (int it = 0; it < 64; it++) {
    if (it + 1 < 64) {
      const ushort_t* src = KTb + (size_t)(it + 1) * 64 * DK;
      ushort_t* dstb = lk[(it + 1) & 1];
#pragma unroll
      for (int kr = 0; kr < 2; kr++) {
        int s = tid + 256 * kr;
        int row = s >> 3, ds = (s & 7) * 8;
        *(uint4v*)(dstb + row * 72 + ds) = *(const uint4v*)(src + (size_t)row * DK + ds);
      }
    }
    const ushort_t* kb = lk[it & 1];
#pragma unroll
    for (int nt = 0; nt < 4; nt++) {
      bf16x8 b0 = lds_frag(kb + (nt * 16 + l15) * 72 + quad * 8);
      bf16x8 b1 = lds_frag(kb + (nt * 16 + l15) * 72 + 32 + quad * 8);
      f32x4 s4 = __builtin_amdgcn_mfma_f32_16x16x32_bf16(a0, b0, zero4, 0, 0, 0);
      s4 = __builtin_amdgcn_mfma_f32_16x16x32_bf16(a1, b1, s4, 0, 0, 0);
      lsum0 += __expf(s4[0]);
      lsum1 += __expf(s4[1]);
      lsum2 += __expf(s4[2]);
      lsum3 += __expf(s4[3]);
    }
    __syncthreads();
  }
#pragma unroll
  for (int off = 1; off < 16; off <<= 1) {
    lsum0 += __shfl_xor(lsum0, off);
    lsum1 += __shfl_xor(lsum1, off);
    lsum2 += __shfl_xor(lsum2, off);
    lsum3 += __shfl_xor(lsum3, off);
  }
  if (l15 == 0) {
    int rr = wv * 16 + quad * 4;
    lrr[rr + 0] = 1.0f / lsum0;
    lrr[rr + 1] = 1.0f / lsum1;
    lrr[rr + 2] = 1.0f / lsum2;
    lrr[rr + 3] = 1.0f / lsum3;
  }
  __syncthreads();
  // scale V[:, i0:i0+64] *= r  (this block owns these columns exclusively)
  {
    int d = tid >> 2, ig = (tid & 3) * 16;
    ushort_t* vp = Vv + ((size_t)b * DK + d) * NTOK + i0 + ig;
    uint4v v0 = *(const uint4v*)vp;
    uint4v v1 = *(const uint4v*)(vp + 8);
    uint4v o0, o1;
    unsigned* vi0 = (unsigned*)&v0;
    unsigned* vi1 = (unsigned*)&v1;
    unsigned* oo0 = (unsigned*)&o0;
    unsigned* oo1 = (unsigned*)&o1;
#pragma unroll
    for (int w = 0; w < 4; w++) {
      float e0 = bf2f((ushort_t)(vi0[w] & 0xffff)) * lrr[ig + 2 * w];
      float e1 = bf2f((ushort_t)(vi0[w] >> 16)) * lrr[ig + 2 * w + 1];
      oo0[w] = (unsigned)f2bf(e0) | ((unsigned)f2bf(e1) << 16);
      float e2 = bf2f((ushort_t)(vi1[w] & 0xffff)) * lrr[ig + 8 + 2 * w];
      float e3 = bf2f((ushort_t)(vi1[w] >> 16)) * lrr[ig + 8 + 2 * w + 1];
      oo1[w] = (unsigned)f2bf(e2) | ((unsigned)f2bf(e3) << 16);
    }
    *(uint4v*)vp = o0;
    *(uint4v*)(vp + 8) = o1;
  }
}

// ------ k3: yT[j][d] = sum_i exp(S)^T V'^T (reg-direct), o=Wout@y*g+x ------
__global__ __launch_bounds__(256) void k_attn(const ushort_t* __restrict__ QT,
                                              const ushort_t* __restrict__ KT,
                                              const ushort_t* __restrict__ Vv,
                                              const ushort_t* __restrict__ Wout,
                                              const float* __restrict__ gammap,
                                              const float* __restrict__ x,
                                              float* __restrict__ outp) {
  const int b = blockIdx.y;
  const int j0 = blockIdx.x * 64;
  const int tid = threadIdx.x;
  const int lane = tid & 63, wv = tid >> 6;
  const int quad = lane >> 4, l15 = lane & 15;

  // 36864-byte pool, manually carved (main phase: lq x2 + lv x2; reduce: rbuf+pbuf)
  __shared__ __align__(16) ushort_t pool[18432];
#define LQ(buf) (pool + (buf) * 4608)
#define LV(buf) (pool + 9216 + (buf) * 4608)
  float* rbuf = (float*)pool;          // 64 x 68 f32 (17408 B), [d][j] layout
  ushort_t* pbuf = pool + 8704;        // byte 17408, 64 x 72 bf16, [j][d] layout

  const ushort_t* KTb = KT + ((size_t)b * NTOK + j0) * DK;
  const ushort_t* QTb = QT + (size_t)b * NTOK * DK;
  const ushort_t* Vb = Vv + (size_t)b * DK * NTOK;

  // stage K tile into LQ(0) region, pull kb frags to registers
#pragma unroll
  for (int kr = 0; kr < 2; kr++) {
    int s = tid + 256 * kr;
    int row = s >> 3, ds = (s & 7) * 8;
    *(uint4v*)(LQ(0) + row * 72 + ds) = *(const uint4v*)(KTb + (size_t)row * DK + ds);
  }
  __syncthreads();
  bf16x8 kb0[4], kb1[4];
#pragma unroll
  for (int nt = 0; nt < 4; nt++) {
    kb0[nt] = lds_frag(LQ(0) + (nt * 16 + l15) * 72 + quad * 8);
    kb1[nt] = lds_frag(LQ(0) + (nt * 16 + l15) * 72 + 32 + quad * 8);
  }
  __syncthreads();
  // stage chunk 0 (Q rows 0..63, V' cols 0..63)
#pragma unroll
  for (int kr = 0; kr < 2; kr++) {
    int s = tid + 256 * kr;
    int row = s >> 3, ds = (s & 7) * 8;
    *(uint4v*)(LQ(0) + row * 72 + ds) = *(const uint4v*)(QTb + (size_t)row * DK + ds);
    *(uint4v*)(LV(0) + row * 72 + ds) = *(const uint4v*)(Vb + (size_t)row * NTOK + ds);
  }
  __syncthreads();

  const f32x4 zero4 = {0.f, 0.f, 0.f, 0.f};
  // per-wave partial yT accumulators: [nt(j16)][dsub(d16)]
  f32x4 yt[4][4];
#pragma unroll
  for (int i = 0; i < 4; i++)
#pragma unroll
    for (int j = 0; j < 4; j++) yt[i][j] = zero4;

  for (int it = 0; it < 64; it++) {
    const int cb = it & 1, nb = cb ^ 1;
    const ushort_t* lqc = LQ(cb);
    const ushort_t* lvc = LV(cb);
    if (it + 1 < 64) {
      const ushort_t* qsrc = QTb + (size_t)(it + 1) * 64 * DK;
      const ushort_t* vsrc = Vb + (it + 1) * 64;
      ushort_t* lqn = LQ(nb);
      ushort_t* lvn = LV(nb);
#pragma unroll
      for (int kr = 0; kr < 2; kr++) {
        int s = tid + 256 * kr;
        int row = s >> 3, ds = (s & 7) * 8;
        *(uint4v*)(lqn + row * 72 + ds) = *(const uint4v*)(qsrc + (size_t)row * DK + ds);
        *(uint4v*)(lvn + row * 72 + ds) = *(const uint4v*)(vsrc + (size_t)row * NTOK + ds);
      }
    }
    // Q A-frags for this wave's 16 i-rows
    bf16x8 a0 = lds_frag(lqc + (wv * 16 + l15) * 72 + quad * 8);
    bf16x8 a1 = lds_frag(lqc + (wv * 16 + l15) * 72 + 32 + quad * 8);
    // V' B-frags (nt-independent): B[k=i local][n=d], lane: V'[dsub*16+l15][wv*16+quad*4+{0..3}]
    short4v vf[4];
#pragma unroll
    for (int dsub = 0; dsub < 4; dsub++)
      vf[dsub] = __builtin_bit_cast(short4v,
          *(const uint2v*)(lvc + (dsub * 16 + l15) * 72 + wv * 16 + quad * 4));
#pragma unroll
    for (int nt = 0; nt < 4; nt++) {
      f32x4 s4 = __builtin_amdgcn_mfma_f32_16x16x32_bf16(a0, kb0[nt], zero4, 0, 0, 0);
      s4 = __builtin_amdgcn_mfma_f32_16x16x32_bf16(a1, kb1[nt], s4, 0, 0, 0);
      // w = exp(s); C-frag (S[i=q*4+r][j=l15]) == A-frag of K16 MFMA as P^T
      uint2v wp;
      wp.x = (unsigned)f2bf(__expf(s4[0])) | ((unsigned)f2bf(__expf(s4[1])) << 16);
      wp.y = (unsigned)f2bf(__expf(s4[2])) | ((unsigned)f2bf(__expf(s4[3])) << 16);
      short4v wf = __builtin_bit_cast(short4v, wp);
#pragma unroll
      for (int dsub = 0; dsub < 4; dsub++)
        yt[nt][dsub] = mfma16(wf, vf[dsub], yt[nt][dsub]);
    }
    __syncthreads();
  }

  // cross-wave reduction of yT partials into rbuf[d][j] (f32, b128 rows)
  // yt[nt][dsub][r] = yT[j=nt*16+quad*4+r][d=dsub*16+l15]
  // rbuf row = dsub*16+l15 (d), cols nt*16+quad*4+{0..3} (j) -> f32x4 contiguous
  if (wv == 0) {
#pragma unroll
    for (int nt = 0; nt < 4; nt++)
#pragma unroll
      for (int dsub = 0; dsub < 4; dsub++)
        *(f32x4*)(rbuf + (dsub * 16 + l15) * 68 + nt * 16 + quad * 4) = yt[nt][dsub];
  }
  __syncthreads();
  if (wv == 1) {
#pragma unroll
    for (int nt = 0; nt < 4; nt++)
#pragma unroll
      for (int dsub = 0; dsub < 4; dsub++) {
        float* p = rbuf + (dsub * 16 + l15) * 68 + nt * 16 + quad * 4;
        *(f32x4*)p = *(const f32x4*)p + yt[nt][dsub];
      }
  }
  __syncthreads();
  if (wv == 2) {
#pragma unroll
    for (int nt = 0; nt < 4; nt++)
#pragma unroll
      for (int dsub = 0; dsub < 4; dsub++) {
        float* p = rbuf + (dsub * 16 + l15) * 68 + nt * 16 + quad * 4;
        *(f32x4*)p = *(const f32x4*)p + yt[nt][dsub];
      }
  }
  __syncthreads();
  if (wv == 3) {
    // final add + convert to bf16 into pbuf[j][d] (stride 72)
#pragma unroll
    for (int nt = 0; nt < 4; nt++)
#pragma unroll
      for (int dsub = 0; dsub < 4; dsub++) {
        const float* p = rbuf + (dsub * 16 + l15) * 68 + nt * 16 + quad * 4;
        f32x4 v4 = *(const f32x4*)p + yt[nt][dsub];
#pragma unroll
        for (int r = 0; r < 4; r++)
          pbuf[(nt * 16 + quad * 4 + r) * 72 + dsub * 16 + l15] = f2bf(v4[r]);
      }
  }
  __syncthreads();

  // epilogue: o = Wout @ y * gamma + x ; pbuf[j][d] is B-operand layout
  bf16x8 yb0[4], yb1[4];
#pragma unroll
  for (int nt = 0; nt < 4; nt++) {
    yb0[nt] = lds_frag(pbuf + (nt * 16 + l15) * 72 + quad * 8);
    yb1[nt] = lds_frag(pbuf + (nt * 16 + l15) * 72 + 32 + quad * 8);
  }
  f32x4 oacc[4][4];
#pragma unroll
  for (int m = 0; m < 4; m++)
#pragma unroll
    for (int nt = 0; nt < 4; nt++) oacc[m][nt] = zero4;
#pragma unroll
  for (int m = 0; m < 4; m++) {
    int c = (wv * 4 + m) * 16 + l15;
    bf16x8 aw0 = __builtin_bit_cast(bf16x8, *(const uint4v*)(Wout + c * DK + quad * 8));
    bf16x8 aw1 = __builtin_bit_cast(bf16x8, *(const uint4v*)(Wout + c * DK + 32 + quad * 8));
#pragma unroll
    for (int nt = 0; nt < 4; nt++) {
      oacc[m][nt] = __builtin_amdgcn_mfma_f32_16x16x32_bf16(aw0, yb0[nt], oacc[m][nt], 0, 0, 0);
      oacc[m][nt] = __builtin_amdgcn_mfma_f32_16x16x32_bf16(aw1, yb1[nt], oacc[m][nt], 0, 0, 0);
    }
  }
  float g = gammap[0];
  const float* xb = x + (size_t)b * DMODEL * NTOK;
  float* ob = outp + (size_t)b * DMODEL * NTOK;
#pragma unroll
  for (int m = 0; m < 4; m++) {
    int cbase = (wv * 4 + m) * 16 + quad * 4;
#pragma unroll
    for (int nt = 0; nt < 4; nt++) {
      int n = j0 + nt * 16 + l15;
#pragma unroll
      for (int r = 0; r < 4; r++) {
        size_t idx = (size_t)(cbase + r) * NTOK + n;
        ob[idx] = oacc[m][nt][r] * g + xb[idx];
      }
    }
  }
#undef LQ
#undef LV
}

extern "C" void kernel_launch(void* const* d_in, const int* in_sizes, int n_in,
                              void* d_out, int out_size, void* d_ws, size_t ws_size,
                              hipStream_t stream) {
  const float* v = (const float*)d_in[0];
  const float* Wqkv = (const float*)d_in[1];
  const float* Wout = (const float*)d_in[2];
  const float* gamma = (const float*)d_in[3];
  float* outp = (float*)d_out;

  ushort_t* xT = (ushort_t*)d_ws;                      // 8*4096*256 bf16
  ushort_t* QT = xT + (size_t)BS * NTOK * DMODEL;      // 8*4096*64
  ushort_t* KT = QT + (size_t)BS * NTOK * DK;
  ushort_t* Vs = KT + (size_t)BS * NTOK * DK;
  ushort_t* Wb = Vs + (size_t)BS * DK * NTOK;          // 192*256 bf16
  ushort_t* Woutb = Wb + 3 * DK * DMODEL;              // 256*64 bf16

  k_convert<<<dim3(256), 256, 0, stream>>>(Wqkv, Wout, Wb, Woutb);
  k_transpose<<<dim3(64, 4, BS), 256, 0, stream>>>(v, xT);
  k_qkv<<<dim3(64, BS), 256, 0, stream>>>(xT, Wb, QT, KT, Vs);
  k_stats<<<dim3(64, BS), 256, 0, stream>>>(QT, KT, Vs);
  k_attn<<<dim3(64, BS), 256, 0, stream>>>(QT, KT, Vs, Woutb, gamma, v, outp);
}

// Round 7
// 215.769 us; speedup vs baseline: 1.1001x; 1.0284x over previous
//
#include <hip/hip_runtime.h>

typedef unsigned short ushort_t;
typedef __bf16 bf16x8 __attribute__((ext_vector_type(8)));
typedef short short4v __attribute__((ext_vector_type(4)));
typedef float f32x4 __attribute__((ext_vector_type(4)));
typedef unsigned int uint4v __attribute__((ext_vector_type(4)));
typedef unsigned int uint2v __attribute__((ext_vector_type(2)));

#define NTOK 4096
#define DMODEL 256
#define DK 64
#define BS 8
#define LN2INV 1.44269504088896f

__device__ __forceinline__ ushort_t f2bf(float f) {
  unsigned u = __builtin_bit_cast(unsigned, f);
  u += 0x7fffu + ((u >> 16) & 1u);
  return (ushort_t)(u >> 16);
}
__device__ __forceinline__ float bf2f(ushort_t s) {
  return __builtin_bit_cast(float, ((unsigned)s) << 16);
}
__device__ __forceinline__ bf16x8 lds_frag(const ushort_t* p) {
  return __builtin_bit_cast(bf16x8, *(const uint4v*)p);
}
__device__ __forceinline__ float fexp2(float x) {
#if __has_builtin(__builtin_amdgcn_exp2f)
  return __builtin_amdgcn_exp2f(x);
#else
  return exp2f(x);
#endif
}
// pack hi16(x) | hi16(y)<<16 in one v_perm (bf16 truncation)
__device__ __forceinline__ unsigned bfpack(float x, float y) {
  return __builtin_amdgcn_perm(__builtin_bit_cast(unsigned, y),
                               __builtin_bit_cast(unsigned, x), 0x07060302u);
}
// K=16 bf16 MFMA: A[m=lane&15][k=quad*4+j], B[k=quad*4+j][n=lane&15], C: n=lane&15, m=quad*4+reg
__device__ __forceinline__ f32x4 mfma16(short4v a, short4v b, f32x4 c) {
#if defined(__HIP_DEVICE_COMPILE__)
#if __has_builtin(__builtin_amdgcn_mfma_f32_16x16x16bf16_1k)
  return __builtin_amdgcn_mfma_f32_16x16x16bf16_1k(a, b, c, 0, 0, 0);
#else
  typedef __bf16 bf16x4 __attribute__((ext_vector_type(4)));
  return __builtin_amdgcn_mfma_f32_16x16x16_bf16(__builtin_bit_cast(bf16x4, a),
                                                 __builtin_bit_cast(bf16x4, b), c, 0, 0, 0);
#endif
#else
  (void)a; (void)b;
  return c;  // host pass: never executed
#endif
}

// ----- k_convert: W fp32 -> bf16; Q rows pre-scaled by 1/ln2 (exp2 trick) --
__global__ __launch_bounds__(256) void k_convert(const float* __restrict__ Wqkv,
                                                 const float* __restrict__ Wout,
                                                 ushort_t* __restrict__ Wb,
                                                 ushort_t* __restrict__ Woutb) {
  int i = blockIdx.x * 256 + threadIdx.x;  // 256 blocks: 65536 total
  if (i < 3 * DK * DMODEL) {
    float w = Wqkv[i];
    if (i < DK * DMODEL) w *= LN2INV;  // Q rows
    Wb[i] = f2bf(w);
  } else {
    int j = i - 3 * DK * DMODEL;
    Woutb[j] = f2bf(Wout[j]);
  }
}

// -------- k0: transpose x[b][c][n] (fp32) -> xT[b][n][c] (bf16) -----------
__global__ __launch_bounds__(256) void k_transpose(const float* __restrict__ x,
                                                   ushort_t* __restrict__ xT) {
  const int b = blockIdx.z;
  const int c0 = blockIdx.y * 64;
  const int n0 = blockIdx.x * 64;
  const int tid = threadIdx.x;
  __shared__ __align__(16) ushort_t t[64 * 72];
  const float* xb = x + (size_t)b * DMODEL * NTOK;
  ushort_t* xTb = xT + (size_t)b * NTOK * DMODEL;
#pragma unroll
  for (int kr = 0; kr < 2; kr++) {
    int s = tid + 256 * kr;
    int c = s >> 3, ns = (s & 7) * 8;
    const float* src = xb + (size_t)(c0 + c) * NTOK + n0 + ns;
    f32x4 a = *(const f32x4*)src;
    f32x4 bq = *(const f32x4*)(src + 4);
    uint4v o;
    o.x = (unsigned)f2bf(a[0]) | ((unsigned)f2bf(a[1]) << 16);
    o.y = (unsigned)f2bf(a[2]) | ((unsigned)f2bf(a[3]) << 16);
    o.z = (unsigned)f2bf(bq[0]) | ((unsigned)f2bf(bq[1]) << 16);
    o.w = (unsigned)f2bf(bq[2]) | ((unsigned)f2bf(bq[3]) << 16);
    *(uint4v*)(t + c * 72 + ns) = o;
  }
  __syncthreads();
#pragma unroll
  for (int kr = 0; kr < 2; kr++) {
    int s = tid + 256 * kr;
    int n = s >> 3, cs = (s & 7) * 8;
    unsigned e0 = t[(cs + 0) * 72 + n], e1 = t[(cs + 1) * 72 + n];
    unsigned e2 = t[(cs + 2) * 72 + n], e3 = t[(cs + 3) * 72 + n];
    unsigned e4 = t[(cs + 4) * 72 + n], e5 = t[(cs + 5) * 72 + n];
    unsigned e6 = t[(cs + 6) * 72 + n], e7 = t[(cs + 7) * 72 + n];
    uint4v o;
    o.x = e0 | (e1 << 16); o.y = e2 | (e3 << 16);
    o.z = e4 | (e5 << 16); o.w = e6 | (e7 << 16);
    *(uint4v*)(xTb + (size_t)(n0 + n) * DMODEL + c0 + cs) = o;
  }
}

// ---------------- k1: qkv = Wqkv @ x ; store QT,KT (transposed) and V -----
__global__ __launch_bounds__(256) void k_qkv(const ushort_t* __restrict__ xT,
                                             const ushort_t* __restrict__ W,
                                             ushort_t* __restrict__ QT,
                                             ushort_t* __restrict__ KT,
                                             ushort_t* __restrict__ Vv) {
  const int b = blockIdx.y;
  const int n0 = blockIdx.x * 64;
  const int tid = threadIdx.x;
  const int lane = tid & 63, wv = tid >> 6;
  const int quad = lane >> 4, l15 = lane & 15;
  __shared__ __align__(16) ushort_t lw[192 * 40];
  __shared__ __align__(16) ushort_t lx[64 * 40];
  f32x4 acc[3][4];
  const f32x4 zero4 = {0.f, 0.f, 0.f, 0.f};
#pragma unroll
  for (int i = 0; i < 3; i++)
#pragma unroll
    for (int j = 0; j < 4; j++) acc[i][j] = zero4;

  const ushort_t* xTb = xT + ((size_t)b * NTOK + n0) * DMODEL;

  for (int c0 = 0; c0 < DMODEL; c0 += 32) {
    __syncthreads();
#pragma unroll
    for (int kr = 0; kr < 3; kr++) {
      int s = tid + 256 * kr;
      int o = s >> 2, cs = (s & 3) * 8;
      *(uint4v*)(lw + o * 40 + cs) = *(const uint4v*)(W + o * DMODEL + c0 + cs);
    }
    {
      int n = tid >> 2, cs = (tid & 3) * 8;
      *(uint4v*)(lx + n * 40 + cs) = *(const uint4v*)(xTb + (size_t)n * DMODEL + c0 + cs);
    }
    __syncthreads();
    bf16x8 bb[4];
#pragma unroll
    for (int nt = 0; nt < 4; nt++) bb[nt] = lds_frag(lx + (nt * 16 + l15) * 40 + quad * 8);
#pragma unroll
    for (int mt = 0; mt < 3; mt++) {
      bf16x8 a = lds_frag(lw + (wv * 48 + mt * 16 + l15) * 40 + quad * 8);
#pragma unroll
      for (int nt = 0; nt < 4; nt++)
        acc[mt][nt] = __builtin_amdgcn_mfma_f32_16x16x32_bf16(a, bb[nt], acc[mt][nt], 0, 0, 0);
    }
  }
#pragma unroll
  for (int mt = 0; mt < 3; mt++) {
    int o = wv * 48 + mt * 16 + quad * 4;
#pragma unroll
    for (int nt = 0; nt < 4; nt++) {
      int n = n0 + nt * 16 + l15;
      f32x4 v4 = acc[mt][nt];
      if (o < 128) {
        ushort_t* dst = (o < 64) ? (QT + ((size_t)b * NTOK + n) * DK + o)
                                 : (KT + ((size_t)b * NTOK + n) * DK + (o - 64));
        uint2v ww;
        ww.x = (unsigned)f2bf(v4[0]) | ((unsigned)f2bf(v4[1]) << 16);
        ww.y = (unsigned)f2bf(v4[2]) | ((unsigned)f2bf(v4[3]) << 16);
        *(uint2v*)dst = ww;
      } else {
        int d = o - 128;
#pragma unroll
        for (int r = 0; r < 4; r++)
          Vv[((size_t)b * DK + d + r) * NTOK + n] = f2bf(v4[r]);
      }
    }
  }
}

// ---- k_rsum: partial row sums over half the j range (j-split, XCD swizzle)
__global__ __launch_bounds__(256) void k_rsum(const ushort_t* __restrict__ QT,
                                              const ushort_t* __restrict__ KT,
                                              float* __restrict__ Rp) {
  const int id = blockIdx.x;                 // 1024 blocks
  const int b = id & 7;                      // same batch -> same XCD (id%8)
  const int rest = id >> 3;
  const int i0 = (rest & 63) * 64;
  const int jh = rest >> 6;                  // j half
  const int tid = threadIdx.x;
  const int lane = tid & 63, wv = tid >> 6;
  const int quad = lane >> 4, l15 = lane & 15;
  __shared__ __align__(16) ushort_t lq[64 * 72];
  __shared__ __align__(16) ushort_t lk[2][64 * 72];
  const ushort_t* QTb = QT + ((size_t)b * NTOK + i0) * DK;
  const ushort_t* KTb = KT + ((size_t)b * NTOK + jh * 2048) * DK;
#pragma unroll
  for (int kr = 0; kr < 2; kr++) {
    int s = tid + 256 * kr;
    int row = s >> 3, ds = (s & 7) * 8;
    *(uint4v*)(lq + row * 72 + ds) = *(const uint4v*)(QTb + (size_t)row * DK + ds);
    *(uint4v*)(lk[0] + row * 72 + ds) = *(const uint4v*)(KTb + (size_t)row * DK + ds);
  }
  __syncthreads();
  bf16x8 a0 = lds_frag(lq + (wv * 16 + l15) * 72 + quad * 8);
  bf16x8 a1 = lds_frag(lq + (wv * 16 + l15) * 72 + 32 + quad * 8);
  float lsum0 = 0.f, lsum1 = 0.f, lsum2 = 0.f, lsum3 = 0.f;
  const f32x4 zero4 = {0.f, 0.f, 0.f, 0.f};
  for (int it = 0; it < 32; it++) {
    if (it + 1 < 32) {
      const ushort_t* src = KTb + (size_t)(it + 1) * 64 * DK;
      ushort_t* dstb = lk[(it + 1) & 1];
#pragma unroll
      for (int kr = 0; kr < 2; kr++) {
        int s = tid + 256 * kr;
        int row = s >> 3, ds = (s & 7) * 8;
        *(uint4v*)(dstb + row * 72 + ds) = *(const uint4v*)(src + (size_t)row * DK + ds);
      }
    }
    const ushort_t* kb = lk[it & 1];
#pragma unroll
    for (int nt = 0; nt < 4; nt++) {
      bf16x8 b0 = lds_frag(kb + (nt * 16 + l15) * 72 + quad * 8);
      bf16x8 b1 = lds_frag(kb + (nt * 16 + l15) * 72 + 32 + quad * 8);
      f32x4 s4 = __builtin_amdgcn_mfma_f32_16x16x32_bf16(a0, b0, zero4, 0, 0, 0);
      s4 = __builtin_amdgcn_mfma_f32_16x16x32_bf16(a1, b1, s4, 0, 0, 0);
      lsum0 += fexp2(s4[0]);
      lsum1 += fexp2(s4[1]);
      lsum2 += fexp2(s4[2]);
      lsum3 += fexp2(s4[3]);
    }
    __syncthreads();
  }
#pragma unroll
  for (int off = 1; off < 16; off <<= 1) {
    lsum0 += __shfl_xor(lsum0, off);
    lsum1 += __shfl_xor(lsum1, off);
    lsum2 += __shfl_xor(lsum2, off);
    lsum3 += __shfl_xor(lsum3, off);
  }
  if (l15 < 4) {
    float v = (l15 == 0) ? lsum0 : (l15 == 1) ? lsum1 : (l15 == 2) ? lsum2 : lsum3;
    Rp[((size_t)(jh * 8 + b)) * NTOK + i0 + wv * 16 + quad * 4 + l15] = v;
  }
}

// ---- k_rmerge: R = 1 / (Rp_half0 + Rp_half1) ----
__global__ __launch_bounds__(256) void k_rmerge(const float* __restrict__ Rp,
                                                float* __restrict__ Rr) {
  int g = blockIdx.x * 256 + threadIdx.x;  // 32768 total -> 128 blocks
  Rr[g] = 1.0f / (Rp[g] + Rp[BS * NTOK + g]);
}

// ---- k_pv: partial yT over half the i range; r folded into exp weights ---
__global__ __launch_bounds__(256) void k_pv(const ushort_t* __restrict__ QT,
                                            const ushort_t* __restrict__ KT,
                                            const ushort_t* __restrict__ Vv,
                                            const float* __restrict__ Rr,
                                            ushort_t* __restrict__ Yp) {
  const int id = blockIdx.x;                 // 1024 blocks
  const int b = id & 7;                      // XCD affinity
  const int rest = id >> 3;
  const int j0 = (rest & 63) * 64;
  const int ih = rest >> 6;                  // i half
  const int tid = threadIdx.x;
  const int lane = tid & 63, wv = tid >> 6;
  const int quad = lane >> 4, l15 = lane & 15;

  __shared__ __align__(16) ushort_t pool[18432];
#define LQ(buf) (pool + (buf) * 4608)
#define LV(buf) (pool + 9216 + (buf) * 4608)
  float* rbuf = (float*)pool;          // 64 x 68 f32, [d][j]
  ushort_t* pbuf = pool + 8704;        // byte 17408, 64 x 72 bf16, [j][d]

  const ushort_t* KTb = KT + ((size_t)b * NTOK + j0) * DK;
  const ushort_t* QTb = QT + ((size_t)b * NTOK + ih * 2048) * DK;
  const ushort_t* Vbb = Vv + (size_t)b * DK * NTOK + ih * 2048;
  const float* Rrb = Rr + (size_t)b * NTOK + ih * 2048;

#pragma unroll
  for (int kr = 0; kr < 2; kr++) {
    int s = tid + 256 * kr;
    int row = s >> 3, ds = (s & 7) * 8;
    *(uint4v*)(LQ(0) + row * 72 + ds) = *(const uint4v*)(KTb + (size_t)row * DK + ds);
  }
  __syncthreads();
  bf16x8 kb0[4], kb1[4];
#pragma unroll
  for (int nt = 0; nt < 4; nt++) {
    kb0[nt] = lds_frag(LQ(0) + (nt * 16 + l15) * 72 + quad * 8);
    kb1[nt] = lds_frag(LQ(0) + (nt * 16 + l15) * 72 + 32 + quad * 8);
  }
  __syncthreads();
#pragma unroll
  for (int kr = 0; kr < 2; kr++) {
    int s = tid + 256 * kr;
    int row = s >> 3, ds = (s & 7) * 8;
    *(uint4v*)(LQ(0) + row * 72 + ds) = *(const uint4v*)(QTb + (size_t)row * DK + ds);
    *(uint4v*)(LV(0) + row * 72 + ds) = *(const uint4v*)(Vbb + (size_t)row * NTOK + ds);
  }
  __syncthreads();

  const f32x4 zero4 = {0.f, 0.f, 0.f, 0.f};
  f32x4 yt[4][4];
#pragma unroll
  for (int i = 0; i < 4; i++)
#pragma unroll
    for (int j = 0; j < 4; j++) yt[i][j] = zero4;

  for (int it = 0; it < 32; it++) {
    const int cb = it & 1, nb = cb ^ 1;
    // prefetch r for this iter's i-window (lane-uniform in l15)
    f32x4 rv = *(const f32x4*)(Rrb + it * 64 + wv * 16 + quad * 4);
    if (it + 1 < 32) {
      const ushort_t* qsrc = QTb + (size_t)(it + 1) * 64 * DK;
#pragma unroll
      for (int kr = 0; kr < 2; kr++) {
        int s = tid + 256 * kr;
        int row = s >> 3, ds = (s & 7) * 8;
        *(uint4v*)(LQ(nb) + row * 72 + ds) = *(const uint4v*)(qsrc + (size_t)row * DK + ds);
        *(uint4v*)(LV(nb) + row * 72 + ds) =
            *(const uint4v*)(Vbb + (size_t)row * NTOK + (it + 1) * 64 + ds);
      }
    }
    bf16x8 a0 = lds_frag(LQ(cb) + (wv * 16 + l15) * 72 + quad * 8);
    bf16x8 a1 = lds_frag(LQ(cb) + (wv * 16 + l15) * 72 + 32 + quad * 8);
    short4v vf[4];
#pragma unroll
    for (int dsub = 0; dsub < 4; dsub++)
      vf[dsub] = __builtin_bit_cast(short4v,
          *(const uint2v*)(LV(cb) + (dsub * 16 + l15) * 72 + wv * 16 + quad * 4));
#pragma unroll
    for (int nt = 0; nt < 4; nt++) {
      f32x4 s4 = __builtin_amdgcn_mfma_f32_16x16x32_bf16(a0, kb0[nt], zero4, 0, 0, 0);
      s4 = __builtin_amdgcn_mfma_f32_16x16x32_bf16(a1, kb1[nt], s4, 0, 0, 0);
      // w = exp2(s') * r_i ; C-frag == A-frag of K16 MFMA as P^T
      uint2v wp;
      wp.x = bfpack(fexp2(s4[0]) * rv[0], fexp2(s4[1]) * rv[1]);
      wp.y = bfpack(fexp2(s4[2]) * rv[2], fexp2(s4[3]) * rv[3]);
      short4v wf = __builtin_bit_cast(short4v, wp);
#pragma unroll
      for (int dsub = 0; dsub < 4; dsub++)
        yt[nt][dsub] = mfma16(wf, vf[dsub], yt[nt][dsub]);
    }
    __syncthreads();
  }

  // cross-wave reduction into rbuf[d][j], then bf16 pbuf[j][d]
  if (wv == 0) {
#pragma unroll
    for (int nt = 0; nt < 4; nt++)
#pragma unroll
      for (int dsub = 0; dsub < 4; dsub++)
        *(f32x4*)(rbuf + (dsub * 16 + l15) * 68 + nt * 16 + quad * 4) = yt[nt][dsub];
  }
  __syncthreads();
  if (wv == 1) {
#pragma unroll
    for (int nt = 0; nt < 4; nt++)
#pragma unroll
      for (int dsub = 0; dsub < 4; dsub++) {
        float* p = rbuf + (dsub * 16 + l15) * 68 + nt * 16 + quad * 4;
        *(f32x4*)p = *(const f32x4*)p + yt[nt][dsub];
      }
  }
  __syncthreads();
  if (wv == 2) {
#pragma unroll
    for (int nt = 0; nt < 4; nt++)
#pragma unroll
      for (int dsub = 0; dsub < 4; dsub++) {
        float* p = rbuf + (dsub * 16 + l15) * 68 + nt * 16 + quad * 4;
        *(f32x4*)p = *(const f32x4*)p + yt[nt][dsub];
      }
  }
  __syncthreads();
  if (wv == 3) {
#pragma unroll
    for (int nt = 0; nt < 4; nt++)
#pragma unroll
      for (int dsub = 0; dsub < 4; dsub++) {
        const float* p = rbuf + (dsub * 16 + l15) * 68 + nt * 16 + quad * 4;
        f32x4 v4 = *(const f32x4*)p + yt[nt][dsub];
#pragma unroll
        for (int r = 0; r < 4; r++)
          pbuf[(nt * 16 + quad * 4 + r) * 72 + dsub * 16 + l15] = f2bf(v4[r]);
      }
  }
  __syncthreads();

  // coalesced copy pbuf -> Yp[ih][b][j0+row][d]
  ushort_t* Ypb = Yp + ((size_t)(ih * 8 + b) * NTOK + j0) * DK;
#pragma unroll
  for (int kr = 0; kr < 2; kr++) {
    int s = tid + 256 * kr;
    int row = s >> 3, c8 = (s & 7) * 8;
    *(uint4v*)(Ypb + (size_t)row * DK + c8) = *(const uint4v*)(pbuf + row * 72 + c8);
  }
#undef LQ
#undef LV
}

// ---- k_out: y = Yp0 + Yp1 ; o = Wout @ y * gamma + x --------------------
__global__ __launch_bounds__(256) void k_out(const ushort_t* __restrict__ Yp,
                                             const ushort_t* __restrict__ Wout,
                                             const float* __restrict__ gammap,
                                             const float* __restrict__ x,
                                             float* __restrict__ outp) {
  const int id = blockIdx.x;                 // 512 blocks
  const int b = id & 7;
  const int n0 = (id >> 3) * 64;
  const int tid = threadIdx.x;
  const int lane = tid & 63, wv = tid >> 6;
  const int quad = lane >> 4, l15 = lane & 15;
  __shared__ __align__(16) ushort_t pbuf[64 * 72];

  const ushort_t* Y0 = Yp + ((size_t)b * NTOK + n0) * DK;
  const ushort_t* Y1 = Yp + ((size_t)(8 + b) * NTOK + n0) * DK;
#pragma unroll
  for (int kr = 0; kr < 2; kr++) {
    int s = tid + 256 * kr;
    int row = s >> 3, c8 = (s & 7) * 8;
    uint4v ua = *(const uint4v*)(Y0 + (size_t)row * DK + c8);
    uint4v ub = *(const uint4v*)(Y1 + (size_t)row * DK + c8);
    uint4v oc;
    unsigned* pa = (unsigned*)&ua;
    unsigned* pb = (unsigned*)&ub;
    unsigned* po = (unsigned*)&oc;
#pragma unroll
    for (int w = 0; w < 4; w++) {
      float lo = bf2f((ushort_t)(pa[w] & 0xffff)) + bf2f((ushort_t)(pb[w] & 0xffff));
      float hi = bf2f((ushort_t)(pa[w] >> 16)) + bf2f((ushort_t)(pb[w] >> 16));
      po[w] = bfpack(lo, hi);
    }
    *(uint4v*)(pbuf + row * 72 + c8) = oc;
  }
  __syncthreads();

  const f32x4 zero4 = {0.f, 0.f, 0.f, 0.f};
  bf16x8 yb0[4], yb1[4];
#pragma unroll
  for (int nt = 0; nt < 4; nt++) {
    yb0[nt] = lds_frag(pbuf + (nt * 16 + l15) * 72 + quad * 8);
    yb1[nt] = lds_frag(pbuf + (nt * 16 + l15) * 72 + 32 + quad * 8);
  }
  f32x4 oacc[4][4];
#pragma unroll
  for (int m = 0; m < 4; m++)
#pragma unroll
    for (int nt = 0; nt < 4; nt++) oacc[m][nt] = zero4;
#pragma unroll
  for (int m = 0; m < 4; m++) {
    int c = (wv * 4 + m) * 16 + l15;
    bf16x8 aw0 = __builtin_bit_cast(bf16x8, *(const uint4v*)(Wout + c * DK + quad * 8));
    bf16x8 aw1 = __builtin_bit_cast(bf16x8, *(const uint4v*)(Wout + c * DK + 32 + quad * 8));
#pragma unroll
    for (int nt = 0; nt < 4; nt++) {
      oacc[m][nt] = __builtin_amdgcn_mfma_f32_16x16x32_bf16(aw0, yb0[nt], oacc[m][nt], 0, 0, 0);
      oacc[m][nt] = __builtin_amdgcn_mfma_f32_16x16x32_bf16(aw1, yb1[nt], oacc[m][nt], 0, 0, 0);
    }
  }
  float g = gammap[0];
  const float* xb = x + (size_t)b * DMODEL * NTOK;
  float* ob = outp + (size_t)b * DMODEL * NTOK;
#pragma unroll
  for (int m = 0; m < 4; m++) {
    int cbase = (wv * 4 + m) * 16 + quad * 4;
#pragma unroll
    for (int nt = 0; nt < 4; nt++) {
      int n = n0 + nt * 16 + l15;
#pragma unroll
      for (int r = 0; r < 4; r++) {
        size_t idx = (size_t)(cbase + r) * NTOK + n;
        ob[idx] = oacc[m][nt][r] * g + xb[idx];
      }
    }
  }
}

extern "C" void kernel_launch(void* const* d_in, const int* in_sizes, int n_in,
                              void* d_out, int out_size, void* d_ws, size_t ws_size,
                              hipStream_t stream) {
  const float* v = (const float*)d_in[0];
  const float* Wqkv = (const float*)d_in[1];
  const float* Wout = (const float*)d_in[2];
  const float* gamma = (const float*)d_in[3];
  float* outp = (float*)d_out;

  ushort_t* xT = (ushort_t*)d_ws;                      // 8*4096*256 bf16
  ushort_t* QT = xT + (size_t)BS * NTOK * DMODEL;      // 8*4096*64
  ushort_t* KT = QT + (size_t)BS * NTOK * DK;
  ushort_t* Vs = KT + (size_t)BS * NTOK * DK;
  ushort_t* Wb = Vs + (size_t)BS * DK * NTOK;          // 192*256
  ushort_t* Woutb = Wb + 3 * DK * DMODEL;              // 256*64
  float* Rp = (float*)(Woutb + DMODEL * DK);           // 2*8*4096 f32
  float* Rr = Rp + 2 * (size_t)BS * NTOK;              // 8*4096 f32
  ushort_t* Yp = (ushort_t*)(Rr + (size_t)BS * NTOK);  // 2*8*4096*64 bf16

  k_convert<<<dim3(256), 256, 0, stream>>>(Wqkv, Wout, Wb, Woutb);
  k_transpose<<<dim3(64, 4, BS), 256, 0, stream>>>(v, xT);
  k_qkv<<<dim3(64, BS), 256, 0, stream>>>(xT, Wb, QT, KT, Vs);
  k_rsum<<<dim3(1024), 256, 0, stream>>>(QT, KT, Rp);
  k_rmerge<<<dim3(128), 256, 0, stream>>>(Rp, Rr);
  k_pv<<<dim3(1024), 256, 0, stream>>>(QT, KT, Vs, Rr, Yp);
  k_out<<<dim3(512), 256, 0, stream>>>(Yp, Woutb, gamma, v, outp);
}